// Round 1
// baseline (103.439 us; speedup 1.0000x reference)
//
#include <hip/hip_runtime.h>
#include <stdint.h>

#define NTOK 2048
#define DMODEL 256
#define NHEAD 4

typedef __attribute__((ext_vector_type(8))) short short8;
typedef __attribute__((ext_vector_type(4))) float f32x4;

#define MFMA16(a, b, c) __builtin_amdgcn_mfma_f32_16x16x32_bf16(a, b, c, 0, 0, 0)

__device__ __forceinline__ unsigned short f2bf(float f) {
  union { float f; unsigned int u; } v; v.f = f;
  unsigned int r = v.u + 0x7FFFu + ((v.u >> 16) & 1u);
  return (unsigned short)(r >> 16);
}

__device__ __forceinline__ f32x4 zero4() {
  f32x4 v; v[0] = 0.f; v[1] = 0.f; v[2] = 0.f; v[3] = 0.f; return v;
}

// ---------------- kernel 1: f32 -> bf16 conversion of x, W, Wo ----------------
__global__ void k_prep(const float* __restrict__ x, const float* __restrict__ W,
                       const float* __restrict__ Wo,
                       unsigned short* __restrict__ xbf, unsigned short* __restrict__ Wbf,
                       unsigned short* __restrict__ Wobf) {
  int e = (blockIdx.x * 256 + threadIdx.x) * 4;
  const float* s; unsigned short* d; int off;
  if (e < 2097152)            { s = x;  d = xbf;  off = e; }
  else if (e < 2097152+65536) { s = W;  d = Wbf;  off = e - 2097152; }
  else                        { s = Wo; d = Wobf; off = e - 2162688; }
  float4 v = *(const float4*)(s + off);
  ushort4 o;
  o.x = f2bf(v.x); o.y = f2bf(v.y); o.z = f2bf(v.z); o.w = f2bf(v.w);
  *(ushort4*)(d + off) = o;
}

// ---------------- kernel 2: pack adj into bitmask ----------------
__global__ void k_pack(const int* __restrict__ adj, unsigned long long* __restrict__ bits) {
  int g = blockIdx.x * 256 + threadIdx.x;
  int v = adj[g];
  unsigned long long m = __ballot(v > 0);
  if ((threadIdx.x & 63) == 0) bits[g >> 6] = m;
}

// ---------------- kernel 3: h = x @ W^T (bf16 MFMA), write hT + src/dst ----------------
// grid: (M/64=128, H=4), block 256. Tile 64 rows(g) x 64 cols(d = head*64+dh).
__global__ void k_gemm1(const unsigned short* __restrict__ xbf, const unsigned short* __restrict__ Wbf,
                        const float* __restrict__ a_src, const float* __restrict__ a_dst,
                        unsigned short* __restrict__ hT, float* __restrict__ srcv,
                        float* __restrict__ dstv) {
  __shared__ float tile[64][65];
  __shared__ float reds[2][4][64];
  const int tid = threadIdx.x, lane = tid & 63, w = tid >> 6;
  const int g0 = blockIdx.x * 64;
  const int hh = blockIdx.y;
  const int n0 = hh * 64;
  const int l15 = lane & 15, kl = (lane >> 4) * 8;

  const unsigned short* arow = xbf + (size_t)(g0 + w * 16 + l15) * 256 + kl;
  const unsigned short* brow = Wbf + (size_t)(n0 + l15) * 256 + kl;

  f32x4 acc[4];
#pragma unroll
  for (int nf = 0; nf < 4; ++nf) acc[nf] = zero4();

#pragma unroll
  for (int k = 0; k < 256; k += 32) {
    short8 a = *(const short8*)(arow + k);
#pragma unroll
    for (int nf = 0; nf < 4; ++nf) {
      short8 b = *(const short8*)(brow + nf * 4096 + k);
      acc[nf] = MFMA16(a, b, acc[nf]);
    }
  }

  const int rbase = w * 16 + (lane >> 4) * 4;
#pragma unroll
  for (int nf = 0; nf < 4; ++nf)
#pragma unroll
    for (int r = 0; r < 4; ++r)
      tile[rbase + r][nf * 16 + l15] = acc[nf][r];
  __syncthreads();

  const int bh = (g0 >> 11) * NHEAD + hh;
  // transposed bf16 write: hT[bh][dh][n]
  {
    const int dh = tid >> 2, nq = (tid & 3) * 16;
    unsigned short* dp = hT + ((size_t)bh * 64 + dh) * 2048 + (g0 & 2047) + nq;
    short8 v0, v1;
#pragma unroll
    for (int q = 0; q < 8; ++q) v0[q] = (short)f2bf(tile[nq + q][dh]);
#pragma unroll
    for (int q = 0; q < 8; ++q) v1[q] = (short)f2bf(tile[nq + 8 + q][dh]);
    *(short8*)dp = v0;
    *(short8*)(dp + 8) = v1;
  }
  // src/dst partial dot over dh
  {
    const int n_loc = tid & 63, q4 = tid >> 6;
    const float* as = a_src + hh * 64 + q4 * 16;
    const float* ad = a_dst + hh * 64 + q4 * 16;
    float ps = 0.f, pd = 0.f;
#pragma unroll
    for (int d2 = 0; d2 < 16; ++d2) {
      float hv = tile[n_loc][q4 * 16 + d2];
      ps += hv * as[d2];
      pd += hv * ad[d2];
    }
    reds[0][q4][n_loc] = ps;
    reds[1][q4][n_loc] = pd;
  }
  __syncthreads();
  if (tid < 64) {
    float s = reds[0][0][tid] + reds[0][1][tid] + reds[0][2][tid] + reds[0][3][tid];
    float d = reds[1][0][tid] + reds[1][1][tid] + reds[1][2][tid] + reds[1][3][tid];
    srcv[(size_t)bh * 2048 + (g0 & 2047) + tid] = s;
    dstv[(size_t)bh * 2048 + (g0 & 2047) + tid] = d;
  }
}

// ---------------- kernel 4: flash-style masked GAT attention ----------------
// grid: (N/64=32, BH=16), block 256 (4 waves x 16 rows). JT=32 per iter.
__global__ void k_attn(const unsigned short* __restrict__ hT, const float* __restrict__ srcv,
                       const float* __restrict__ dstv, const unsigned long long* __restrict__ bits,
                       unsigned short* __restrict__ attb) {
  __shared__ float dst_s[2048];
  __shared__ unsigned long long adjw[64][33];
  __shared__ float src_s[64];
  const int tid = threadIdx.x, lane = tid & 63, w = tid >> 6;
  const int bh = blockIdx.y;
  const int i0 = blockIdx.x * 64;

  {
    const float* dsrc = dstv + (size_t)bh * 2048;
#pragma unroll
    for (int t = 0; t < 2; ++t) {
      int idx = (tid + t * 256) * 4;
      *(float4*)(dst_s + idx) = *(const float4*)(dsrc + idx);
    }
    if (tid < 64) src_s[tid] = srcv[(size_t)bh * 2048 + i0 + tid];
#pragma unroll
    for (int t = 0; t < 8; ++t) {
      int q = tid + t * 256;  // 0..2047
      adjw[q >> 5][q & 31] = bits[(size_t)(i0 + (q >> 5)) * 32 + (q & 31)];
    }
  }
  __syncthreads();

  const int l15 = lane & 15, kl = (lane >> 4) * 8;
  const int il = w * 16 + l15;
  const float src_i = src_s[il];
  const unsigned short* hrow0 = hT + (size_t)bh * 64 * 2048 + (size_t)l15 * 2048 + kl;

  float m = -3.0e38f, lsum = 0.f;
  f32x4 acc[4];
#pragma unroll
  for (int nf = 0; nf < 4; ++nf) acc[nf] = zero4();
  unsigned long long word = 0ull;

  for (int j0 = 0; j0 < 2048; j0 += 32) {
    if ((j0 & 63) == 0) word = adjw[il][j0 >> 6];
    const unsigned int byte = (unsigned int)(word >> ((j0 & 32) + kl)) & 0xFFu;
    float4 d0 = *(const float4*)(dst_s + j0 + kl);
    float4 d1 = *(const float4*)(dst_s + j0 + kl + 4);
    float dv[8] = {d0.x, d0.y, d0.z, d0.w, d1.x, d1.y, d1.z, d1.w};
    float s[8];
    float tmax = -3.0e38f;
#pragma unroll
    for (int t = 0; t < 8; ++t) {
      float e = src_i + dv[t];
      e = fmaxf(e, 0.2f * e);           // leaky_relu(0.2)
      e = ((byte >> t) & 1u) ? e : -3.0e38f;
      s[t] = e;
      tmax = fmaxf(tmax, e);
    }
    tmax = fmaxf(tmax, __shfl_xor(tmax, 16));
    tmax = fmaxf(tmax, __shfl_xor(tmax, 32));
    const float mold = m;
    m = fmaxf(m, tmax);
    if (__any(m > mold)) {
      const float scale = __expf(mold - m);
      lsum *= scale;
      const int rb = (lane >> 4) * 4;
      float sc[4];
#pragma unroll
      for (int r = 0; r < 4; ++r) sc[r] = __shfl(scale, rb + r);
#pragma unroll
      for (int nf = 0; nf < 4; ++nf)
#pragma unroll
        for (int r = 0; r < 4; ++r) acc[nf][r] *= sc[r];
    }
    float psum = 0.f;
    short8 af;
#pragma unroll
    for (int t = 0; t < 8; ++t) {
      float p = ((byte >> t) & 1u) ? __expf(s[t] - m) : 0.f;
      psum += p;
      af[t] = (short)f2bf(p);
    }
    lsum += psum;
#pragma unroll
    for (int nf = 0; nf < 4; ++nf) {
      short8 bfrag = *(const short8*)(hrow0 + (size_t)nf * 32768 + j0);
      acc[nf] = MFMA16(af, bfrag, acc[nf]);
    }
  }

  lsum += __shfl_xor(lsum, 16);
  lsum += __shfl_xor(lsum, 32);
  const int rb = (lane >> 4) * 4;
  float linv[4];
#pragma unroll
  for (int r = 0; r < 4; ++r) {
    float lr = __shfl(lsum, rb + r);
    linv[r] = 1.f / lr;
  }
  const int b = bh >> 2, hh2 = bh & 3;
#pragma unroll
  for (int nf = 0; nf < 4; ++nf)
#pragma unroll
    for (int r = 0; r < 4; ++r) {
      int i = i0 + w * 16 + rb + r;
      size_t o = ((size_t)(b * 2048 + i)) * 256 + hh2 * 64 + nf * 16 + l15;
      attb[o] = f2bf(acc[nf][r] * linv[r]);
    }
}

// ---------------- kernel 5: out2 = att @ Wo^T + bo; y = LN(x + out2) ----------------
// grid: 256 blocks, 32 rows each, full 256 cols; 4 waves: (row-half, col-half) split.
__global__ void k_gemm2(const unsigned short* __restrict__ attb, const unsigned short* __restrict__ Wobf,
                        const float* __restrict__ bo, const float* __restrict__ x,
                        const float* __restrict__ gamma, const float* __restrict__ beta,
                        float* __restrict__ out) {
  __shared__ float tile[32][260];
  const int tid = threadIdx.x, lane = tid & 63, w = tid >> 6;
  const int g0 = blockIdx.x * 32;
  const int l15 = lane & 15, kl = (lane >> 4) * 8;
  const int rw = (w & 1) * 16;
  const int cb = (w >> 1) * 128;

  const unsigned short* arow = attb + (size_t)(g0 + rw + l15) * 256 + kl;
  const unsigned short* brow = Wobf + (size_t)(cb + l15) * 256 + kl;

  f32x4 acc[8];
#pragma unroll
  for (int nf = 0; nf < 8; ++nf) acc[nf] = zero4();

#pragma unroll
  for (int k = 0; k < 256; k += 32) {
    short8 a = *(const short8*)(arow + k);
#pragma unroll
    for (int nf = 0; nf < 8; ++nf) {
      short8 b = *(const short8*)(brow + (size_t)nf * 4096 + k);
      acc[nf] = MFMA16(a, b, acc[nf]);
    }
  }

  const int rb = rw + (lane >> 4) * 4;
#pragma unroll
  for (int nf = 0; nf < 8; ++nf)
#pragma unroll
    for (int r = 0; r < 4; ++r) {
      int c = cb + nf * 16 + l15;
      tile[rb + r][c] = acc[nf][r] + bo[c];
    }
  __syncthreads();

  const float4 gv = *(const float4*)(gamma + lane * 4);
  const float4 bv = *(const float4*)(beta + lane * 4);
  for (int r = 0; r < 8; ++r) {
    const int gl = w * 8 + r;
    const size_t g = g0 + gl;
    float4 xv = *(const float4*)(x + g * 256 + lane * 4);
    float4 tv = *(float4*)(&tile[gl][lane * 4]);
    float v0 = tv.x + xv.x, v1 = tv.y + xv.y, v2 = tv.z + xv.z, v3 = tv.w + xv.w;
    float sum = v0 + v1 + v2 + v3;
    float sq = v0 * v0 + v1 * v1 + v2 * v2 + v3 * v3;
#pragma unroll
    for (int off = 32; off >= 1; off >>= 1) {
      sum += __shfl_xor(sum, off);
      sq += __shfl_xor(sq, off);
    }
    const float mu = sum * (1.f / 256.f);
    const float var = sq * (1.f / 256.f) - mu * mu;
    const float rs = rsqrtf(var + 1e-5f);
    float4 o;
    o.x = (v0 - mu) * rs * gv.x + bv.x;
    o.y = (v1 - mu) * rs * gv.y + bv.y;
    o.z = (v2 - mu) * rs * gv.z + bv.z;
    o.w = (v3 - mu) * rs * gv.w + bv.w;
    *(float4*)(out + g * 256 + lane * 4) = o;
  }
}

extern "C" void kernel_launch(void* const* d_in, const int* in_sizes, int n_in,
                              void* d_out, int out_size, void* d_ws, size_t ws_size,
                              hipStream_t stream) {
  const float* x      = (const float*)d_in[0];
  const int*   adj    = (const int*)d_in[1];
  const float* W      = (const float*)d_in[2];
  const float* a_src  = (const float*)d_in[3];
  const float* a_dst  = (const float*)d_in[4];
  const float* Wo     = (const float*)d_in[5];
  const float* bo     = (const float*)d_in[6];
  const float* gamma  = (const float*)d_in[7];
  const float* beta   = (const float*)d_in[8];
  float* out = (float*)d_out;

  char* ws = (char*)d_ws;
  unsigned short* xbf       = (unsigned short*)(ws);
  unsigned short* hT        = (unsigned short*)(ws + (4u << 20));
  unsigned short* attb      = (unsigned short*)(ws + (8u << 20));
  unsigned long long* bits  = (unsigned long long*)(ws + (12u << 20));
  unsigned short* Wbf       = (unsigned short*)(ws + (12u << 20) + (512u << 10));
  unsigned short* Wobf      = (unsigned short*)(ws + (12u << 20) + (640u << 10));
  float* srcv               = (float*)(ws + (12u << 20) + (768u << 10));
  float* dstv               = (float*)(ws + (12u << 20) + (896u << 10));

  k_prep<<<2176, 256, 0, stream>>>(x, W, Wo, xbf, Wbf, Wobf);
  k_pack<<<16384, 256, 0, stream>>>(adj, bits);
  k_gemm1<<<dim3(128, 4), 256, 0, stream>>>(xbf, Wbf, a_src, a_dst, hT, srcv, dstv);
  k_attn<<<dim3(32, 16), 256, 0, stream>>>(hT, srcv, dstv, bits, attb);
  k_gemm2<<<256, 256, 0, stream>>>(attb, Wobf, bo, x, gamma, beta, out);
}

// Round 2
// 99.207 us; speedup vs baseline: 1.0427x; 1.0427x over previous
//
#include <hip/hip_runtime.h>
#include <stdint.h>

#define NTOK 2048
#define DMODEL 256
#define NHEAD 4

typedef __attribute__((ext_vector_type(8))) short short8;
typedef __attribute__((ext_vector_type(4))) float f32x4;

#define MFMA16(a, b, c) __builtin_amdgcn_mfma_f32_16x16x32_bf16(a, b, c, 0, 0, 0)

#if __has_builtin(__builtin_amdgcn_exp2f)
#define EXP2(x) __builtin_amdgcn_exp2f(x)
#else
#define EXP2(x) __expf((x) * 0.6931471805599453f)
#endif

__device__ __forceinline__ unsigned short f2bf(float f) {
  union { float f; unsigned int u; } v; v.f = f;
  unsigned int r = v.u + 0x7FFFu + ((v.u >> 16) & 1u);
  return (unsigned short)(r >> 16);
}

__device__ __forceinline__ f32x4 zero4() {
  f32x4 v; v[0] = 0.f; v[1] = 0.f; v[2] = 0.f; v[3] = 0.f; return v;
}

// ---------------- kernel 1: bf16 conversion of x,W,Wo + adj bitmask pack ----------------
__global__ void k_prep_pack(const float* __restrict__ x, const float* __restrict__ W,
                            const float* __restrict__ Wo, const int* __restrict__ adj,
                            unsigned short* __restrict__ xbf, unsigned short* __restrict__ Wbf,
                            unsigned short* __restrict__ Wobf,
                            unsigned long long* __restrict__ bits) {
  const int b = blockIdx.x;
  if (b < 2176) {
    int e = (b * 256 + threadIdx.x) * 4;
    const float* s; unsigned short* d; int off;
    if (e < 2097152)              { s = x;  d = xbf;  off = e; }
    else if (e < 2097152 + 65536) { s = W;  d = Wbf;  off = e - 2097152; }
    else                          { s = Wo; d = Wobf; off = e - 2162688; }
    float4 v = *(const float4*)(s + off);
    ushort4 o;
    o.x = f2bf(v.x); o.y = f2bf(v.y); o.z = f2bf(v.z); o.w = f2bf(v.w);
    *(ushort4*)(d + off) = o;
  } else {
    int g = (b - 2176) * 256 + threadIdx.x;
    int v = adj[g];
    unsigned long long m = __ballot(v > 0);
    if ((threadIdx.x & 63) == 0) bits[g >> 6] = m;
  }
}

// ---------------- kernel 2: h = x @ W^T (bf16 MFMA), write hT + src/dst ----------------
// grid: (M/64=128, H=4), block 256. Tile 64 rows(g) x 64 cols(d = head*64+dh).
__global__ void k_gemm1(const unsigned short* __restrict__ xbf, const unsigned short* __restrict__ Wbf,
                        const float* __restrict__ a_src, const float* __restrict__ a_dst,
                        unsigned short* __restrict__ hT, float* __restrict__ srcv,
                        float* __restrict__ dstv) {
  __shared__ float tile[64][65];
  __shared__ float reds[2][4][64];
  const int tid = threadIdx.x, lane = tid & 63, w = tid >> 6;
  const int g0 = blockIdx.x * 64;
  const int hh = blockIdx.y;
  const int n0 = hh * 64;
  const int l15 = lane & 15, kl = (lane >> 4) * 8;

  const unsigned short* arow = xbf + (size_t)(g0 + w * 16 + l15) * 256 + kl;
  const unsigned short* brow = Wbf + (size_t)(n0 + l15) * 256 + kl;

  f32x4 acc[4];
#pragma unroll
  for (int nf = 0; nf < 4; ++nf) acc[nf] = zero4();

#pragma unroll
  for (int k = 0; k < 256; k += 32) {
    short8 a = *(const short8*)(arow + k);
#pragma unroll
    for (int nf = 0; nf < 4; ++nf) {
      short8 b = *(const short8*)(brow + nf * 4096 + k);
      acc[nf] = MFMA16(a, b, acc[nf]);
    }
  }

  const int rbase = w * 16 + (lane >> 4) * 4;
#pragma unroll
  for (int nf = 0; nf < 4; ++nf)
#pragma unroll
    for (int r = 0; r < 4; ++r)
      tile[rbase + r][nf * 16 + l15] = acc[nf][r];
  __syncthreads();

  const int bh = (g0 >> 11) * NHEAD + hh;
  // transposed bf16 write: hT[bh][dh][n]
  {
    const int dh = tid >> 2, nq = (tid & 3) * 16;
    unsigned short* dp = hT + ((size_t)bh * 64 + dh) * 2048 + (g0 & 2047) + nq;
    short8 v0, v1;
#pragma unroll
    for (int q = 0; q < 8; ++q) v0[q] = (short)f2bf(tile[nq + q][dh]);
#pragma unroll
    for (int q = 0; q < 8; ++q) v1[q] = (short)f2bf(tile[nq + 8 + q][dh]);
    *(short8*)dp = v0;
    *(short8*)(dp + 8) = v1;
  }
  // src/dst partial dot over dh
  {
    const int n_loc = tid & 63, q4 = tid >> 6;
    const float* as = a_src + hh * 64 + q4 * 16;
    const float* ad = a_dst + hh * 64 + q4 * 16;
    float ps = 0.f, pd = 0.f;
#pragma unroll
    for (int d2 = 0; d2 < 16; ++d2) {
      float hv = tile[n_loc][q4 * 16 + d2];
      ps += hv * as[d2];
      pd += hv * ad[d2];
    }
    reds[0][q4][n_loc] = ps;
    reds[1][q4][n_loc] = pd;
  }
  __syncthreads();
  if (tid < 64) {
    float s = reds[0][0][tid] + reds[0][1][tid] + reds[0][2][tid] + reds[0][3][tid];
    float d = reds[1][0][tid] + reds[1][1][tid] + reds[1][2][tid] + reds[1][3][tid];
    srcv[(size_t)bh * 2048 + (g0 & 2047) + tid] = s;
    dstv[(size_t)bh * 2048 + (g0 & 2047) + tid] = d;
  }
}

// ---------------- kernel 3: masked GAT attention, precomputed row-max bound ----------------
// grid: (N/32=64, BH=16), block 256 = 4 waves: (row-half rg, j-half jh).
// No online softmax: m_i = leaky(src_i + max_j dst_j) is a valid upper bound (rank-1 scores).
// All values pre-scaled by log2(e) so p = exp2(s - m). Linear partial combine across j-halves.
__global__ void k_attn(const unsigned short* __restrict__ hT, const float* __restrict__ srcv,
                       const float* __restrict__ dstv, const unsigned long long* __restrict__ bits,
                       unsigned short* __restrict__ attb) {
  __shared__ float dst_s[2048];
  __shared__ unsigned long long adjw[32][33];
  __shared__ float src_s[32];
  __shared__ float red[4];
  __shared__ float comb[2][64][17];
  const int tid = threadIdx.x, lane = tid & 63, w = tid >> 6;
  const int bh = blockIdx.y;
  const int i0 = blockIdx.x * 32;
  const float LOG2E = 1.4426950408889634f;

  // preamble: load dst (scaled) + block max, src (scaled), adj words
  float lmax = -3.0e38f;
  {
    const float* dsrc = dstv + (size_t)bh * 2048;
#pragma unroll
    for (int t = 0; t < 2; ++t) {
      int idx = (tid + t * 256) * 4;
      float4 v = *(const float4*)(dsrc + idx);
      v.x *= LOG2E; v.y *= LOG2E; v.z *= LOG2E; v.w *= LOG2E;
      *(float4*)(dst_s + idx) = v;
      lmax = fmaxf(fmaxf(fmaxf(lmax, v.x), fmaxf(v.y, v.z)), v.w);
    }
#pragma unroll
    for (int off = 32; off >= 1; off >>= 1) lmax = fmaxf(lmax, __shfl_xor(lmax, off));
    if (lane == 0) red[w] = lmax;
    if (tid < 32) src_s[tid] = srcv[(size_t)bh * 2048 + i0 + tid] * LOG2E;
#pragma unroll
    for (int t = 0; t < 4; ++t) {
      int q = tid + t * 256;  // 0..1023
      adjw[q >> 5][q & 31] = bits[(size_t)(i0 + (q >> 5)) * 32 + (q & 31)];
    }
  }
  __syncthreads();
  const float dmax = fmaxf(fmaxf(red[0], red[1]), fmaxf(red[2], red[3]));

  const int l15 = lane & 15, kl = (lane >> 4) * 8;
  const int rg = w & 1, jh = w >> 1;
  const int il = rg * 16 + l15;
  const float src_i = src_s[il];
  const float sm0 = src_i + dmax;
  const float m = fmaxf(sm0, 0.2f * sm0);  // scaled leaky upper bound of row max
  const unsigned short* hrow0 = hT + (size_t)bh * 131072 + (size_t)l15 * 2048 + kl;

  float lsum = 0.f;
  f32x4 acc[4];
#pragma unroll
  for (int nf = 0; nf < 4; ++nf) acc[nf] = zero4();
  unsigned long long word = 0ull;

  const int jbeg = jh * 1024, jend = jbeg + 1024;
  for (int j0 = jbeg; j0 < jend; j0 += 32) {
    if ((j0 & 63) == 0) word = adjw[il][j0 >> 6];
    const unsigned int byte = (unsigned int)(word >> ((j0 & 32) + kl)) & 0xFFu;
    float4 d0 = *(const float4*)(dst_s + j0 + kl);
    float4 d1 = *(const float4*)(dst_s + j0 + kl + 4);
    float dv[8] = {d0.x, d0.y, d0.z, d0.w, d1.x, d1.y, d1.z, d1.w};
    float p[8];
#pragma unroll
    for (int t = 0; t < 8; ++t) {
      float e = src_i + dv[t];
      e = fmaxf(e, 0.2f * e);                       // leaky_relu (scaled domain)
      float s = ((byte >> t) & 1u) ? e : -3.0e38f;  // mask
      p[t] = EXP2(s - m);
      lsum += p[t];
    }
    union { short8 s8; unsigned int u32[4]; } af;
#pragma unroll
    for (int t = 0; t < 4; ++t)
      asm("v_cvt_pk_bf16_f32 %0, %1, %2" : "=v"(af.u32[t]) : "v"(p[2 * t]), "v"(p[2 * t + 1]));
#pragma unroll
    for (int nf = 0; nf < 4; ++nf) {
      short8 bfrag = *(const short8*)(hrow0 + (size_t)nf * 32768 + j0);
      acc[nf] = MFMA16(af.s8, bfrag, acc[nf]);
    }
  }

  // reduce lsum across k-groups (rows replicated 4x per wave)
  lsum += __shfl_xor(lsum, 16);
  lsum += __shfl_xor(lsum, 32);

  // combine j-halves
  if (jh == 1) {
#pragma unroll
    for (int nf = 0; nf < 4; ++nf)
#pragma unroll
      for (int r = 0; r < 4; ++r) comb[rg][lane][nf * 4 + r] = acc[nf][r];
    comb[rg][lane][16] = lsum;
  }
  __syncthreads();
  if (jh == 0) {
#pragma unroll
    for (int nf = 0; nf < 4; ++nf)
#pragma unroll
      for (int r = 0; r < 4; ++r) acc[nf][r] += comb[rg][lane][nf * 4 + r];
    lsum += comb[rg][lane][16];

    const int rb = (lane >> 4) * 4;
    float linv[4];
#pragma unroll
    for (int r = 0; r < 4; ++r) {
      float lr = __shfl(lsum, rb + r);
      linv[r] = 1.f / lr;
    }
    const int b = bh >> 2, hh2 = bh & 3;
#pragma unroll
    for (int nf = 0; nf < 4; ++nf)
#pragma unroll
      for (int r = 0; r < 4; ++r) {
        int i = i0 + rg * 16 + rb + r;
        size_t o = ((size_t)(b * 2048 + i)) * 256 + hh2 * 64 + nf * 16 + l15;
        attb[o] = f2bf(acc[nf][r] * linv[r]);
      }
  }
}

// ---------------- kernel 4: out2 = att @ Wo^T + bo; y = LN(x + out2) ----------------
__global__ void k_gemm2(const unsigned short* __restrict__ attb, const unsigned short* __restrict__ Wobf,
                        const float* __restrict__ bo, const float* __restrict__ x,
                        const float* __restrict__ gamma, const float* __restrict__ beta,
                        float* __restrict__ out) {
  __shared__ float tile[32][260];
  const int tid = threadIdx.x, lane = tid & 63, w = tid >> 6;
  const int g0 = blockIdx.x * 32;
  const int l15 = lane & 15, kl = (lane >> 4) * 8;
  const int rw = (w & 1) * 16;
  const int cb = (w >> 1) * 128;

  const unsigned short* arow = attb + (size_t)(g0 + rw + l15) * 256 + kl;
  const unsigned short* brow = Wobf + (size_t)(cb + l15) * 256 + kl;

  f32x4 acc[8];
#pragma unroll
  for (int nf = 0; nf < 8; ++nf) acc[nf] = zero4();

#pragma unroll
  for (int k = 0; k < 256; k += 32) {
    short8 a = *(const short8*)(arow + k);
#pragma unroll
    for (int nf = 0; nf < 8; ++nf) {
      short8 b = *(const short8*)(brow + (size_t)nf * 4096 + k);
      acc[nf] = MFMA16(a, b, acc[nf]);
    }
  }

  const int rb = rw + (lane >> 4) * 4;
#pragma unroll
  for (int nf = 0; nf < 8; ++nf)
#pragma unroll
    for (int r = 0; r < 4; ++r) {
      int c = cb + nf * 16 + l15;
      tile[rb + r][c] = acc[nf][r] + bo[c];
    }
  __syncthreads();

  const float4 gv = *(const float4*)(gamma + lane * 4);
  const float4 bv = *(const float4*)(beta + lane * 4);
  for (int r = 0; r < 8; ++r) {
    const int gl = w * 8 + r;
    const size_t g = g0 + gl;
    float4 xv = *(const float4*)(x + g * 256 + lane * 4);
    float4 tv = *(float4*)(&tile[gl][lane * 4]);
    float v0 = tv.x + xv.x, v1 = tv.y + xv.y, v2 = tv.z + xv.z, v3 = tv.w + xv.w;
    float sum = v0 + v1 + v2 + v3;
    float sq = v0 * v0 + v1 * v1 + v2 * v2 + v3 * v3;
#pragma unroll
    for (int off = 32; off >= 1; off >>= 1) {
      sum += __shfl_xor(sum, off);
      sq += __shfl_xor(sq, off);
    }
    const float mu = sum * (1.f / 256.f);
    const float var = sq * (1.f / 256.f) - mu * mu;
    const float rs = rsqrtf(var + 1e-5f);
    float4 o;
    o.x = (v0 - mu) * rs * gv.x + bv.x;
    o.y = (v1 - mu) * rs * gv.y + bv.y;
    o.z = (v2 - mu) * rs * gv.z + bv.z;
    o.w = (v3 - mu) * rs * gv.w + bv.w;
    *(float4*)(out + g * 256 + lane * 4) = o;
  }
}

extern "C" void kernel_launch(void* const* d_in, const int* in_sizes, int n_in,
                              void* d_out, int out_size, void* d_ws, size_t ws_size,
                              hipStream_t stream) {
  const float* x      = (const float*)d_in[0];
  const int*   adj    = (const int*)d_in[1];
  const float* W      = (const float*)d_in[2];
  const float* a_src  = (const float*)d_in[3];
  const float* a_dst  = (const float*)d_in[4];
  const float* Wo     = (const float*)d_in[5];
  const float* bo     = (const float*)d_in[6];
  const float* gamma  = (const float*)d_in[7];
  const float* beta   = (const float*)d_in[8];
  float* out = (float*)d_out;

  char* ws = (char*)d_ws;
  unsigned short* xbf       = (unsigned short*)(ws);
  unsigned short* hT        = (unsigned short*)(ws + (4u << 20));
  unsigned short* attb      = (unsigned short*)(ws + (8u << 20));
  unsigned long long* bits  = (unsigned long long*)(ws + (12u << 20));
  unsigned short* Wbf       = (unsigned short*)(ws + (12u << 20) + (512u << 10));
  unsigned short* Wobf      = (unsigned short*)(ws + (12u << 20) + (640u << 10));
  float* srcv               = (float*)(ws + (12u << 20) + (768u << 10));
  float* dstv               = (float*)(ws + (12u << 20) + (896u << 10));

  k_prep_pack<<<18560, 256, 0, stream>>>(x, W, Wo, adj, xbf, Wbf, Wobf, bits);
  k_gemm1<<<dim3(128, 4), 256, 0, stream>>>(xbf, Wbf, a_src, a_dst, hT, srcv, dstv);
  k_attn<<<dim3(64, 16), 256, 0, stream>>>(hT, srcv, dstv, bits, attb);
  k_gemm2<<<256, 256, 0, stream>>>(attb, Wobf, bo, x, gamma, beta, out);
}

// Round 3
// 69.533 us; speedup vs baseline: 1.4876x; 1.4268x over previous
//
#include <hip/hip_runtime.h>
#include <stdint.h>

#define NTOK 2048
#define DMODEL 256
#define NHEAD 4

typedef __attribute__((ext_vector_type(8))) short short8;
typedef __attribute__((ext_vector_type(4))) float f32x4;

#define MFMA16(a, b, c) __builtin_amdgcn_mfma_f32_16x16x32_bf16(a, b, c, 0, 0, 0)

#if __has_builtin(__builtin_amdgcn_exp2f)
#define EXP2(x) __builtin_amdgcn_exp2f(x)
#else
#define EXP2(x) __expf((x) * 0.6931471805599453f)
#endif

__device__ __forceinline__ unsigned short f2bf(float f) {
  union { float f; unsigned int u; } v; v.f = f;
  unsigned int r = v.u + 0x7FFFu + ((v.u >> 16) & 1u);
  return (unsigned short)(r >> 16);
}

__device__ __forceinline__ f32x4 zero4() {
  f32x4 v; v[0] = 0.f; v[1] = 0.f; v[2] = 0.f; v[3] = 0.f; return v;
}

// ---------------- kernel 1: bf16 conversion of x,W,Wo + adj bitmask pack ----------------
__global__ void k_prep_pack(const float* __restrict__ x, const float* __restrict__ W,
                            const float* __restrict__ Wo, const int* __restrict__ adj,
                            unsigned short* __restrict__ xbf, unsigned short* __restrict__ Wbf,
                            unsigned short* __restrict__ Wobf,
                            unsigned long long* __restrict__ bits) {
  const int b = blockIdx.x;
  if (b < 2176) {
    int e = (b * 256 + threadIdx.x) * 4;
    const float* s; unsigned short* d; int off;
    if (e < 2097152)              { s = x;  d = xbf;  off = e; }
    else if (e < 2097152 + 65536) { s = W;  d = Wbf;  off = e - 2097152; }
    else                          { s = Wo; d = Wobf; off = e - 2162688; }
    float4 v = *(const float4*)(s + off);
    ushort4 o;
    o.x = f2bf(v.x); o.y = f2bf(v.y); o.z = f2bf(v.z); o.w = f2bf(v.w);
    *(ushort4*)(d + off) = o;
  } else {
    int g = (b - 2176) * 256 + threadIdx.x;
    int v = adj[g];
    unsigned long long m = __ballot(v > 0);
    if ((threadIdx.x & 63) == 0) bits[g >> 6] = m;
  }
}

// ---------------- kernel 2: h = x @ W^T (bf16 MFMA), write hT + src/dst ----------------
__global__ void k_gemm1(const unsigned short* __restrict__ xbf, const unsigned short* __restrict__ Wbf,
                        const float* __restrict__ a_src, const float* __restrict__ a_dst,
                        unsigned short* __restrict__ hT, float* __restrict__ srcv,
                        float* __restrict__ dstv) {
  __shared__ float tile[64][65];
  __shared__ float reds[2][4][64];
  const int tid = threadIdx.x, lane = tid & 63, w = tid >> 6;
  const int g0 = blockIdx.x * 64;
  const int hh = blockIdx.y;
  const int n0 = hh * 64;
  const int l15 = lane & 15, kl = (lane >> 4) * 8;

  const unsigned short* arow = xbf + (size_t)(g0 + w * 16 + l15) * 256 + kl;
  const unsigned short* brow = Wbf + (size_t)(n0 + l15) * 256 + kl;

  f32x4 acc[4];
#pragma unroll
  for (int nf = 0; nf < 4; ++nf) acc[nf] = zero4();

#pragma unroll
  for (int k = 0; k < 256; k += 32) {
    short8 a = *(const short8*)(arow + k);
#pragma unroll
    for (int nf = 0; nf < 4; ++nf) {
      short8 b = *(const short8*)(brow + nf * 4096 + k);
      acc[nf] = MFMA16(a, b, acc[nf]);
    }
  }

  const int rbase = w * 16 + (lane >> 4) * 4;
#pragma unroll
  for (int nf = 0; nf < 4; ++nf)
#pragma unroll
    for (int r = 0; r < 4; ++r)
      tile[rbase + r][nf * 16 + l15] = acc[nf][r];
  __syncthreads();

  const int bh = (g0 >> 11) * NHEAD + hh;
  // transposed bf16 write: hT[bh][dh][n]
  {
    const int dh = tid >> 2, nq = (tid & 3) * 16;
    unsigned short* dp = hT + ((size_t)bh * 64 + dh) * 2048 + (g0 & 2047) + nq;
    short8 v0, v1;
#pragma unroll
    for (int q = 0; q < 8; ++q) v0[q] = (short)f2bf(tile[nq + q][dh]);
#pragma unroll
    for (int q = 0; q < 8; ++q) v1[q] = (short)f2bf(tile[nq + 8 + q][dh]);
    *(short8*)dp = v0;
    *(short8*)(dp + 8) = v1;
  }
  // src/dst partial dot over dh
  {
    const int n_loc = tid & 63, q4 = tid >> 6;
    const float* as = a_src + hh * 64 + q4 * 16;
    const float* ad = a_dst + hh * 64 + q4 * 16;
    float ps = 0.f, pd = 0.f;
#pragma unroll
    for (int d2 = 0; d2 < 16; ++d2) {
      float hv = tile[n_loc][q4 * 16 + d2];
      ps += hv * as[d2];
      pd += hv * ad[d2];
    }
    reds[0][q4][n_loc] = ps;
    reds[1][q4][n_loc] = pd;
  }
  __syncthreads();
  if (tid < 64) {
    float s = reds[0][0][tid] + reds[0][1][tid] + reds[0][2][tid] + reds[0][3][tid];
    float d = reds[1][0][tid] + reds[1][1][tid] + reds[1][2][tid] + reds[1][3][tid];
    srcv[(size_t)bh * 2048 + (g0 & 2047) + tid] = s;
    dstv[(size_t)bh * 2048 + (g0 & 2047) + tid] = d;
  }
}

// ---------------- kernel 3: masked GAT attention, LDS-staged hT tiles ----------------
// grid: 512 blocks (XCD-swizzled -> bh-per-XCD L2 locality), block 256 = 4 waves x 16 rows.
// Full-j walk per block; hT tile (64dh x 128j bf16, XOR-swizzled) double-buffered in LDS.
// Row max bound m = leaky(src_i + max_j dst_j) precomputed (rank-1 scores, no online SM).
// Row sums via a 5th MFMA against a ones-vector (lands in acc row layout; no shuffles).
__global__ __launch_bounds__(256) void k_attn(
    const unsigned short* __restrict__ hT, const float* __restrict__ srcv,
    const float* __restrict__ dstv, const unsigned long long* __restrict__ bits,
    unsigned short* __restrict__ attb) {
  __shared__ float dst_s[2048];
  __shared__ unsigned long long adjw[64][33];
  __shared__ float src_s[64];
  __shared__ float red[4];
  __shared__ unsigned short kv[2][8192];  // [buf][dh*128 + swizzled j], 16 KB each

  const int tid = threadIdx.x, lane = tid & 63, w = tid >> 6;
  // bijective XCD swizzle: 512 blocks, 8 XCDs -> each XCD gets 2 consecutive bh
  const int orig = blockIdx.x;
  const int lid = (orig & 7) * 64 + (orig >> 3);
  const int bh = lid >> 5;
  const int i0 = (lid & 31) * 64;
  const float LOG2E = 1.4426950408889634f;

  // ---- preamble: dst (scaled) + global max, src (scaled), adj words ----
  float lmax = -3.0e38f;
  {
    const float* dsrc = dstv + (size_t)bh * 2048;
#pragma unroll
    for (int t = 0; t < 2; ++t) {
      int idx = (tid + t * 256) * 4;
      float4 v = *(const float4*)(dsrc + idx);
      v.x *= LOG2E; v.y *= LOG2E; v.z *= LOG2E; v.w *= LOG2E;
      *(float4*)(dst_s + idx) = v;
      lmax = fmaxf(fmaxf(fmaxf(lmax, v.x), fmaxf(v.y, v.z)), v.w);
    }
#pragma unroll
    for (int off = 32; off >= 1; off >>= 1) lmax = fmaxf(lmax, __shfl_xor(lmax, off));
    if (lane == 0) red[w] = lmax;
    if (tid < 64) src_s[tid] = srcv[(size_t)bh * 2048 + i0 + tid] * LOG2E;
#pragma unroll
    for (int t = 0; t < 8; ++t) {
      int q = tid + t * 256;  // 0..2047
      adjw[q >> 5][q & 31] = bits[(size_t)(i0 + (q >> 5)) * 32 + (q & 31)];
    }
  }

  // ---- stage tile 0 (reg -> swizzled LDS) ----
  const unsigned short* hTb = hT + (size_t)bh * 131072;
  short8 st0, st1, st2, st3;
  const int c0 = tid, c1 = 256 + tid, c2 = 512 + tid, c3 = 768 + tid;
  const int dh0 = c0 >> 4, ci0 = c0 & 15;
  const int dh1 = c1 >> 4, ci1 = c1 & 15;
  const int dh2 = c2 >> 4, ci2 = c2 & 15;
  const int dh3 = c3 >> 4, ci3 = c3 & 15;
  const int wof0 = dh0 * 128 + ((ci0 ^ (dh0 & 7)) << 3);
  const int wof1 = dh1 * 128 + ((ci1 ^ (dh1 & 7)) << 3);
  const int wof2 = dh2 * 128 + ((ci2 ^ (dh2 & 7)) << 3);
  const int wof3 = dh3 * 128 + ((ci3 ^ (dh3 & 7)) << 3);
  st0 = *(const short8*)(hTb + dh0 * 2048 + ci0 * 8);
  st1 = *(const short8*)(hTb + dh1 * 2048 + ci1 * 8);
  st2 = *(const short8*)(hTb + dh2 * 2048 + ci2 * 8);
  st3 = *(const short8*)(hTb + dh3 * 2048 + ci3 * 8);
  *(short8*)(&kv[0][wof0]) = st0;
  *(short8*)(&kv[0][wof1]) = st1;
  *(short8*)(&kv[0][wof2]) = st2;
  *(short8*)(&kv[0][wof3]) = st3;
  __syncthreads();
  const float dmax = fmaxf(fmaxf(red[0], red[1]), fmaxf(red[2], red[3]));

  const int l15 = lane & 15, klg = lane >> 4, kl = klg * 8;
  const int il = w * 16 + l15;
  const float src_i = src_s[il];
  const float sm0 = src_i + dmax;
  const float m = fmaxf(sm0, 0.2f * sm0);  // scaled leaky upper bound of row max
  const int xm = l15 & 7;                  // (nf*16+l15)&7, nf-independent

  short8 ones;
#pragma unroll
  for (int q = 0; q < 8; ++q) ones[q] = (short)0x3F80;

  float lv = m; (void)lv;
  f32x4 acc[4], accs;
#pragma unroll
  for (int nf = 0; nf < 4; ++nf) acc[nf] = zero4();
  accs = zero4();

  for (int t = 0; t < 16; ++t) {
    const int cur = t & 1;
    if (t < 15) {  // issue-early loads for tile t+1 (T14)
      const unsigned short* src = hTb + (t + 1) * 128;
      st0 = *(const short8*)(src + dh0 * 2048 + ci0 * 8);
      st1 = *(const short8*)(src + dh1 * 2048 + ci1 * 8);
      st2 = *(const short8*)(src + dh2 * 2048 + ci2 * 8);
      st3 = *(const short8*)(src + dh3 * 2048 + ci3 * 8);
    }
    const unsigned long long w0 = adjw[il][2 * t], w1 = adjw[il][2 * t + 1];
    const unsigned short* kvb = kv[cur];
    const float* dsb = dst_s + t * 128;
#pragma unroll
    for (int jj = 0; jj < 4; ++jj) {
      float4 d0 = *(const float4*)(dsb + jj * 32 + kl);
      float4 d1 = *(const float4*)(dsb + jj * 32 + kl + 4);
      const unsigned int byte =
          (unsigned int)(((jj < 2 ? w0 : w1) >> ((jj & 1) * 32 + kl))) & 0xFFu;
      float dv[8] = {d0.x, d0.y, d0.z, d0.w, d1.x, d1.y, d1.z, d1.w};
      float p[8];
#pragma unroll
      for (int t8 = 0; t8 < 8; ++t8) {
        float e = src_i + dv[t8];
        e = fmaxf(e, 0.2f * e);                            // leaky (scaled domain)
        float s = ((byte >> t8) & 1u) ? (e - m) : -3.0e38f;
        p[t8] = EXP2(s);
      }
      union { short8 s8; unsigned int u32[4]; } af;
#pragma unroll
      for (int q = 0; q < 4; ++q)
        asm("v_cvt_pk_bf16_f32 %0, %1, %2" : "=v"(af.u32[q]) : "v"(p[2 * q]), "v"(p[2 * q + 1]));
      const int chunk = (((jj * 4 + klg) ^ xm) << 3) + l15 * 128;
      accs = MFMA16(af.s8, ones, accs);
#pragma unroll
      for (int nf = 0; nf < 4; ++nf) {
        short8 bfrag = *(const short8*)(kvb + nf * 2048 + chunk);
        acc[nf] = MFMA16(af.s8, bfrag, acc[nf]);
      }
    }
    __syncthreads();
    if (t < 15) {
      unsigned short* kvn = kv[cur ^ 1];
      *(short8*)(&kvn[wof0]) = st0;
      *(short8*)(&kvn[wof1]) = st1;
      *(short8*)(&kvn[wof2]) = st2;
      *(short8*)(&kvn[wof3]) = st3;
    }
    __syncthreads();
  }

  // ---- epilogue: normalize by MFMA row sums (already in acc row layout) ----
  const int rb = klg * 4;
  float linv[4];
#pragma unroll
  for (int r = 0; r < 4; ++r) linv[r] = 1.f / accs[r];
  const int b = bh >> 2, hh2 = bh & 3;
#pragma unroll
  for (int nf = 0; nf < 4; ++nf)
#pragma unroll
    for (int r = 0; r < 4; ++r) {
      int i = i0 + w * 16 + rb + r;
      size_t o = ((size_t)(b * 2048 + i)) * 256 + hh2 * 64 + nf * 16 + l15;
      attb[o] = f2bf(acc[nf][r] * linv[r]);
    }
}

// ---------------- kernel 4: out2 = att @ Wo^T + bo; y = LN(x + out2) ----------------
__global__ void k_gemm2(const unsigned short* __restrict__ attb, const unsigned short* __restrict__ Wobf,
                        const float* __restrict__ bo, const float* __restrict__ x,
                        const float* __restrict__ gamma, const float* __restrict__ beta,
                        float* __restrict__ out) {
  __shared__ float tile[32][260];
  const int tid = threadIdx.x, lane = tid & 63, w = tid >> 6;
  const int g0 = blockIdx.x * 32;
  const int l15 = lane & 15, kl = (lane >> 4) * 8;
  const int rw = (w & 1) * 16;
  const int cb = (w >> 1) * 128;

  const unsigned short* arow = attb + (size_t)(g0 + rw + l15) * 256 + kl;
  const unsigned short* brow = Wobf + (size_t)(cb + l15) * 256 + kl;

  f32x4 acc[8];
#pragma unroll
  for (int nf = 0; nf < 8; ++nf) acc[nf] = zero4();

#pragma unroll
  for (int k = 0; k < 256; k += 32) {
    short8 a = *(const short8*)(arow + k);
#pragma unroll
    for (int nf = 0; nf < 8; ++nf) {
      short8 b = *(const short8*)(brow + (size_t)nf * 4096 + k);
      acc[nf] = MFMA16(a, b, acc[nf]);
    }
  }

  const int rb = rw + (lane >> 4) * 4;
#pragma unroll
  for (int nf = 0; nf < 8; ++nf)
#pragma unroll
    for (int r = 0; r < 4; ++r) {
      int c = cb + nf * 16 + l15;
      tile[rb + r][c] = acc[nf][r] + bo[c];
    }
  __syncthreads();

  const float4 gv = *(const float4*)(gamma + lane * 4);
  const float4 bv = *(const float4*)(beta + lane * 4);
  for (int r = 0; r < 8; ++r) {
    const int gl = w * 8 + r;
    const size_t g = g0 + gl;
    float4 xv = *(const float4*)(x + g * 256 + lane * 4);
    float4 tv = *(float4*)(&tile[gl][lane * 4]);
    float v0 = tv.x + xv.x, v1 = tv.y + xv.y, v2 = tv.z + xv.z, v3 = tv.w + xv.w;
    float sum = v0 + v1 + v2 + v3;
    float sq = v0 * v0 + v1 * v1 + v2 * v2 + v3 * v3;
#pragma unroll
    for (int off = 32; off >= 1; off >>= 1) {
      sum += __shfl_xor(sum, off);
      sq += __shfl_xor(sq, off);
    }
    const float mu = sum * (1.f / 256.f);
    const float var = sq * (1.f / 256.f) - mu * mu;
    const float rs = rsqrtf(var + 1e-5f);
    float4 o;
    o.x = (v0 - mu) * rs * gv.x + bv.x;
    o.y = (v1 - mu) * rs * gv.y + bv.y;
    o.z = (v2 - mu) * rs * gv.z + bv.z;
    o.w = (v3 - mu) * rs * gv.w + bv.w;
    *(float4*)(out + g * 256 + lane * 4) = o;
  }
}

extern "C" void kernel_launch(void* const* d_in, const int* in_sizes, int n_in,
                              void* d_out, int out_size, void* d_ws, size_t ws_size,
                              hipStream_t stream) {
  const float* x      = (const float*)d_in[0];
  const int*   adj    = (const int*)d_in[1];
  const float* W      = (const float*)d_in[2];
  const float* a_src  = (const float*)d_in[3];
  const float* a_dst  = (const float*)d_in[4];
  const float* Wo     = (const float*)d_in[5];
  const float* bo     = (const float*)d_in[6];
  const float* gamma  = (const float*)d_in[7];
  const float* beta   = (const float*)d_in[8];
  float* out = (float*)d_out;

  char* ws = (char*)d_ws;
  unsigned short* xbf       = (unsigned short*)(ws);
  unsigned short* hT        = (unsigned short*)(ws + (4u << 20));
  unsigned short* attb      = (unsigned short*)(ws + (8u << 20));
  unsigned long long* bits  = (unsigned long long*)(ws + (12u << 20));
  unsigned short* Wbf       = (unsigned short*)(ws + (12u << 20) + (512u << 10));
  unsigned short* Wobf      = (unsigned short*)(ws + (12u << 20) + (640u << 10));
  float* srcv               = (float*)(ws + (12u << 20) + (768u << 10));
  float* dstv               = (float*)(ws + (12u << 20) + (896u << 10));

  k_prep_pack<<<18560, 256, 0, stream>>>(x, W, Wo, adj, xbf, Wbf, Wobf, bits);
  k_gemm1<<<dim3(128, 4), 256, 0, stream>>>(xbf, Wbf, a_src, a_dst, hT, srcv, dstv);
  k_attn<<<512, 256, 0, stream>>>(hT, srcv, dstv, bits, attb);
  k_gemm2<<<256, 256, 0, stream>>>(attb, Wobf, bo, x, gamma, beta, out);
}

// Round 4
// 65.487 us; speedup vs baseline: 1.5795x; 1.0618x over previous
//
#include <hip/hip_runtime.h>
#include <stdint.h>

#define NTOK 2048
#define DMODEL 256
#define NHEAD 4

typedef __attribute__((ext_vector_type(8))) short short8;
typedef __attribute__((ext_vector_type(4))) float f32x4;

#define MFMA16(a, b, c) __builtin_amdgcn_mfma_f32_16x16x32_bf16(a, b, c, 0, 0, 0)

#if __has_builtin(__builtin_amdgcn_exp2f)
#define EXP2(x) __builtin_amdgcn_exp2f(x)
#else
#define EXP2(x) __expf((x) * 0.6931471805599453f)
#endif

__device__ __forceinline__ unsigned short f2bf(float f) {
  union { float f; unsigned int u; } v; v.f = f;
  unsigned int r = v.u + 0x7FFFu + ((v.u >> 16) & 1u);
  return (unsigned short)(r >> 16);
}

__device__ __forceinline__ f32x4 zero4() {
  f32x4 v; v[0] = 0.f; v[1] = 0.f; v[2] = 0.f; v[3] = 0.f; return v;
}

// ---------------- kernel 1: bf16 conversion of x,W,Wo + adj bitmask pack ----------------
__global__ void k_prep_pack(const float* __restrict__ x, const float* __restrict__ W,
                            const float* __restrict__ Wo, const int* __restrict__ adj,
                            unsigned short* __restrict__ xbf, unsigned short* __restrict__ Wbf,
                            unsigned short* __restrict__ Wobf,
                            unsigned long long* __restrict__ bits) {
  const int b = blockIdx.x;
  if (b < 2176) {
    int e = (b * 256 + threadIdx.x) * 4;
    const float* s; unsigned short* d; int off;
    if (e < 2097152)              { s = x;  d = xbf;  off = e; }
    else if (e < 2097152 + 65536) { s = W;  d = Wbf;  off = e - 2097152; }
    else                          { s = Wo; d = Wobf; off = e - 2162688; }
    float4 v = *(const float4*)(s + off);
    ushort4 o;
    o.x = f2bf(v.x); o.y = f2bf(v.y); o.z = f2bf(v.z); o.w = f2bf(v.w);
    *(ushort4*)(d + off) = o;
  } else {
    int g = (b - 2176) * 256 + threadIdx.x;
    int v = adj[g];
    unsigned long long m = __ballot(v > 0);
    if ((threadIdx.x & 63) == 0) bits[g >> 6] = m;
  }
}

// ---------------- kernel 2: h = x @ W^T (bf16 MFMA), write hT + src/dst ----------------
__global__ void k_gemm1(const unsigned short* __restrict__ xbf, const unsigned short* __restrict__ Wbf,
                        const float* __restrict__ a_src, const float* __restrict__ a_dst,
                        unsigned short* __restrict__ hT, float* __restrict__ srcv,
                        float* __restrict__ dstv) {
  __shared__ float tile[64][65];
  __shared__ float reds[2][4][64];
  const int tid = threadIdx.x, lane = tid & 63, w = tid >> 6;
  const int g0 = blockIdx.x * 64;
  const int hh = blockIdx.y;
  const int n0 = hh * 64;
  const int l15 = lane & 15, kl = (lane >> 4) * 8;

  const unsigned short* arow = xbf + (size_t)(g0 + w * 16 + l15) * 256 + kl;
  const unsigned short* brow = Wbf + (size_t)(n0 + l15) * 256 + kl;

  f32x4 acc[4];
#pragma unroll
  for (int nf = 0; nf < 4; ++nf) acc[nf] = zero4();

#pragma unroll
  for (int k = 0; k < 256; k += 32) {
    short8 a = *(const short8*)(arow + k);
#pragma unroll
    for (int nf = 0; nf < 4; ++nf) {
      short8 b = *(const short8*)(brow + nf * 4096 + k);
      acc[nf] = MFMA16(a, b, acc[nf]);
    }
  }

  const int rbase = w * 16 + (lane >> 4) * 4;
#pragma unroll
  for (int nf = 0; nf < 4; ++nf)
#pragma unroll
    for (int r = 0; r < 4; ++r)
      tile[rbase + r][nf * 16 + l15] = acc[nf][r];
  __syncthreads();

  const int bh = (g0 >> 11) * NHEAD + hh;
  // transposed bf16 write: hT[bh][dh][n]
  {
    const int dh = tid >> 2, nq = (tid & 3) * 16;
    unsigned short* dp = hT + ((size_t)bh * 64 + dh) * 2048 + (g0 & 2047) + nq;
    short8 v0, v1;
#pragma unroll
    for (int q = 0; q < 8; ++q) v0[q] = (short)f2bf(tile[nq + q][dh]);
#pragma unroll
    for (int q = 0; q < 8; ++q) v1[q] = (short)f2bf(tile[nq + 8 + q][dh]);
    *(short8*)dp = v0;
    *(short8*)(dp + 8) = v1;
  }
  // src/dst partial dot over dh
  {
    const int n_loc = tid & 63, q4 = tid >> 6;
    const float* as = a_src + hh * 64 + q4 * 16;
    const float* ad = a_dst + hh * 64 + q4 * 16;
    float ps = 0.f, pd = 0.f;
#pragma unroll
    for (int d2 = 0; d2 < 16; ++d2) {
      float hv = tile[n_loc][q4 * 16 + d2];
      ps += hv * as[d2];
      pd += hv * ad[d2];
    }
    reds[0][q4][n_loc] = ps;
    reds[1][q4][n_loc] = pd;
  }
  __syncthreads();
  if (tid < 64) {
    float s = reds[0][0][tid] + reds[0][1][tid] + reds[0][2][tid] + reds[0][3][tid];
    float d = reds[1][0][tid] + reds[1][1][tid] + reds[1][2][tid] + reds[1][3][tid];
    srcv[(size_t)bh * 2048 + (g0 & 2047) + tid] = s;
    dstv[(size_t)bh * 2048 + (g0 & 2047) + tid] = d;
  }
}

// ---------------- kernel 3: masked GAT attention v3 ----------------
// 512 threads = 8 waves = 2 row-groups(32 rows) x 4 j-slices(32 j of each 128-j tile).
// kv B-frags shared across 2 row-halves per wave (half the LDS reads per row);
// single barrier per tile (true double-buffer); j-slice partials combined via LDS.
__global__ __launch_bounds__(512, 4) void k_attn(
    const unsigned short* __restrict__ hT, const float* __restrict__ srcv,
    const float* __restrict__ dstv, const unsigned long long* __restrict__ bits,
    unsigned short* __restrict__ attb) {
  __shared__ float dst_s[2048];
  __shared__ unsigned long long adjw[64][33];
  __shared__ float src_s[64];
  __shared__ float red[8];
  __shared__ unsigned short kv[2][8192];  // [buf][dh*128 + swizzled j], 16 KB each
  __shared__ float comb[2][64][40];

  const int tid = threadIdx.x, lane = tid & 63, w = tid >> 6;
  // bijective XCD swizzle: 512 blocks -> 64 consecutive lids per XCD (2 bh per XCD)
  const int orig = blockIdx.x;
  const int lid = (orig & 7) * 64 + (orig >> 3);
  const int bh = lid >> 5;
  const int i0 = (lid & 31) * 64;
  const int rg = w & 1, js = w >> 1;
  const float LOG2E = 1.4426950408889634f;

  // ---- preamble: dst (scaled) + global max, src (scaled), adj words ----
  float lmax = -3.0e38f;
  {
    const float* dsrc = dstv + (size_t)bh * 2048;
    int idx = tid * 4;
    float4 v = *(const float4*)(dsrc + idx);
    v.x *= LOG2E; v.y *= LOG2E; v.z *= LOG2E; v.w *= LOG2E;
    *(float4*)(dst_s + idx) = v;
    lmax = fmaxf(fmaxf(v.x, v.y), fmaxf(v.z, v.w));
#pragma unroll
    for (int off = 32; off >= 1; off >>= 1) lmax = fmaxf(lmax, __shfl_xor(lmax, off));
    if (lane == 0) red[w] = lmax;
    if (tid < 64) src_s[tid] = srcv[(size_t)bh * 2048 + i0 + tid] * LOG2E;
#pragma unroll
    for (int t = 0; t < 4; ++t) {
      int q = tid + t * 512;  // 0..2047
      adjw[q >> 5][q & 31] = bits[(size_t)(i0 + (q >> 5)) * 32 + (q & 31)];
    }
  }

  // ---- stage tile 0 (reg -> swizzled LDS); 2 chunks per thread ----
  const unsigned short* hTb = hT + (size_t)bh * 131072;
  const int c0 = tid, c1 = tid + 512;
  const int dh0 = c0 >> 4, ci0 = c0 & 15;
  const int dh1 = c1 >> 4, ci1 = c1 & 15;
  const int wof0 = dh0 * 128 + ((ci0 ^ (dh0 & 7)) << 3);
  const int wof1 = dh1 * 128 + ((ci1 ^ (dh1 & 7)) << 3);
  short8 st0 = *(const short8*)(hTb + dh0 * 2048 + ci0 * 8);
  short8 st1 = *(const short8*)(hTb + dh1 * 2048 + ci1 * 8);
  *(short8*)(&kv[0][wof0]) = st0;
  *(short8*)(&kv[0][wof1]) = st1;
  __syncthreads();
  const float dmax = fmaxf(fmaxf(fmaxf(red[0], red[1]), fmaxf(red[2], red[3])),
                           fmaxf(fmaxf(red[4], red[5]), fmaxf(red[6], red[7])));

  const int l15 = lane & 15, klg = lane >> 4, kl = klg * 8;
  const float src0 = src_s[rg * 32 + l15];
  const float src1 = src_s[rg * 32 + 16 + l15];
  const float sa0 = src0 + dmax, sa1 = src1 + dmax;
  const float m0 = fmaxf(sa0, 0.2f * sa0);  // scaled leaky upper bound of row max
  const float m1 = fmaxf(sa1, 0.2f * sa1);
  const int xm = l15 & 7;
  const int chunk = (((js * 4 + klg) ^ xm) << 3) + l15 * 128;
  const int il0 = rg * 32 + l15, il1 = il0 + 16;
  const int wsel = js >> 1, wsh = (js & 1) * 32 + kl;

  short8 ones;
#pragma unroll
  for (int q = 0; q < 8; ++q) ones[q] = (short)0x3F80;

  f32x4 acc[2][4], accs[2];
#pragma unroll
  for (int rh = 0; rh < 2; ++rh) {
    accs[rh] = zero4();
#pragma unroll
    for (int nf = 0; nf < 4; ++nf) acc[rh][nf] = zero4();
  }

  for (int t = 0; t < 16; ++t) {
    const int cur = t & 1;
    if (t < 15) {  // issue-early global loads for tile t+1 (T14)
      const unsigned short* src = hTb + (t + 1) * 128;
      st0 = *(const short8*)(src + dh0 * 2048 + ci0 * 8);
      st1 = *(const short8*)(src + dh1 * 2048 + ci1 * 8);
    }
    const unsigned short* kvb = kv[cur];
    short8 bf[4];
#pragma unroll
    for (int nf = 0; nf < 4; ++nf) bf[nf] = *(const short8*)(kvb + nf * 2048 + chunk);
    const float* dsb = dst_s + t * 128 + js * 32;
    float4 d0 = *(const float4*)(dsb + kl);
    float4 d1 = *(const float4*)(dsb + kl + 4);
    float dv[8] = {d0.x, d0.y, d0.z, d0.w, d1.x, d1.y, d1.z, d1.w};
#pragma unroll
    for (int rh = 0; rh < 2; ++rh) {
      const float src_i = rh ? src1 : src0;
      const float m = rh ? m1 : m0;
      const unsigned long long word = adjw[rh ? il1 : il0][2 * t + wsel];
      const unsigned int byte = (unsigned int)(word >> wsh) & 0xFFu;
      float p[8];
#pragma unroll
      for (int t8 = 0; t8 < 8; ++t8) {
        float e = src_i + dv[t8];
        e = fmaxf(e, 0.2f * e);                            // leaky (scaled domain)
        float s = ((byte >> t8) & 1u) ? (e - m) : -3.0e38f;
        p[t8] = EXP2(s);
      }
      union { short8 s8; unsigned int u32[4]; } af;
#pragma unroll
      for (int q = 0; q < 4; ++q)
        asm("v_cvt_pk_bf16_f32 %0, %1, %2" : "=v"(af.u32[q]) : "v"(p[2 * q]), "v"(p[2 * q + 1]));
      accs[rh] = MFMA16(af.s8, ones, accs[rh]);
#pragma unroll
      for (int nf = 0; nf < 4; ++nf) acc[rh][nf] = MFMA16(af.s8, bf[nf], acc[rh][nf]);
    }
    if (t < 15) {  // write next tile into the other buffer; one barrier per tile
      unsigned short* kvn = kv[cur ^ 1];
      *(short8*)(&kvn[wof0]) = st0;
      *(short8*)(&kvn[wof1]) = st1;
    }
    __syncthreads();
  }

  // ---- combine j-slices (js=1..3 into js=0) ----
#pragma unroll 1
  for (int s = 1; s < 4; ++s) {
    if (js == s) {
#pragma unroll
      for (int rh = 0; rh < 2; ++rh) {
#pragma unroll
        for (int nf = 0; nf < 4; ++nf)
#pragma unroll
          for (int r = 0; r < 4; ++r) comb[rg][lane][rh * 20 + nf * 4 + r] = acc[rh][nf][r];
#pragma unroll
        for (int r = 0; r < 4; ++r) comb[rg][lane][rh * 20 + 16 + r] = accs[rh][r];
      }
    }
    __syncthreads();
    if (js == 0) {
#pragma unroll
      for (int rh = 0; rh < 2; ++rh) {
#pragma unroll
        for (int nf = 0; nf < 4; ++nf)
#pragma unroll
          for (int r = 0; r < 4; ++r) acc[rh][nf][r] += comb[rg][lane][rh * 20 + nf * 4 + r];
#pragma unroll
        for (int r = 0; r < 4; ++r) accs[rh][r] += comb[rg][lane][rh * 20 + 16 + r];
      }
    }
    __syncthreads();
  }

  // ---- epilogue: normalize + store (js==0 waves only) ----
  if (js == 0) {
    const int rb = klg * 4;
    const int b = bh >> 2, hh2 = bh & 3;
#pragma unroll
    for (int rh = 0; rh < 2; ++rh) {
      float linv[4];
#pragma unroll
      for (int r = 0; r < 4; ++r) linv[r] = 1.f / accs[rh][r];
#pragma unroll
      for (int nf = 0; nf < 4; ++nf)
#pragma unroll
        for (int r = 0; r < 4; ++r) {
          int i = i0 + rg * 32 + rh * 16 + rb + r;
          size_t o = ((size_t)(b * 2048 + i)) * 256 + hh2 * 64 + nf * 16 + l15;
          attb[o] = f2bf(acc[rh][nf][r] * linv[r]);
        }
    }
  }
}

// ---------------- kernel 4: out2 = att @ Wo^T + bo; y = LN(x + out2) ----------------
__global__ void k_gemm2(const unsigned short* __restrict__ attb, const unsigned short* __restrict__ Wobf,
                        const float* __restrict__ bo, const float* __restrict__ x,
                        const float* __restrict__ gamma, const float* __restrict__ beta,
                        float* __restrict__ out) {
  __shared__ float tile[32][260];
  const int tid = threadIdx.x, lane = tid & 63, w = tid >> 6;
  const int g0 = blockIdx.x * 32;
  const int l15 = lane & 15, kl = (lane >> 4) * 8;
  const int rw = (w & 1) * 16;
  const int cb = (w >> 1) * 128;

  const unsigned short* arow = attb + (size_t)(g0 + rw + l15) * 256 + kl;
  const unsigned short* brow = Wobf + (size_t)(cb + l15) * 256 + kl;

  f32x4 acc[8];
#pragma unroll
  for (int nf = 0; nf < 8; ++nf) acc[nf] = zero4();

#pragma unroll
  for (int k = 0; k < 256; k += 32) {
    short8 a = *(const short8*)(arow + k);
#pragma unroll
    for (int nf = 0; nf < 8; ++nf) {
      short8 b = *(const short8*)(brow + (size_t)nf * 4096 + k);
      acc[nf] = MFMA16(a, b, acc[nf]);
    }
  }

  const int rb = rw + (lane >> 4) * 4;
#pragma unroll
  for (int nf = 0; nf < 8; ++nf)
#pragma unroll
    for (int r = 0; r < 4; ++r) {
      int c = cb + nf * 16 + l15;
      tile[rb + r][c] = acc[nf][r] + bo[c];
    }
  __syncthreads();

  const float4 gv = *(const float4*)(gamma + lane * 4);
  const float4 bv = *(const float4*)(beta + lane * 4);
  for (int r = 0; r < 8; ++r) {
    const int gl = w * 8 + r;
    const size_t g = g0 + gl;
    float4 xv = *(const float4*)(x + g * 256 + lane * 4);
    float4 tv = *(float4*)(&tile[gl][lane * 4]);
    float v0 = tv.x + xv.x, v1 = tv.y + xv.y, v2 = tv.z + xv.z, v3 = tv.w + xv.w;
    float sum = v0 + v1 + v2 + v3;
    float sq = v0 * v0 + v1 * v1 + v2 * v2 + v3 * v3;
#pragma unroll
    for (int off = 32; off >= 1; off >>= 1) {
      sum += __shfl_xor(sum, off);
      sq += __shfl_xor(sq, off);
    }
    const float mu = sum * (1.f / 256.f);
    const float var = sq * (1.f / 256.f) - mu * mu;
    const float rs = rsqrtf(var + 1e-5f);
    float4 o;
    o.x = (v0 - mu) * rs * gv.x + bv.x;
    o.y = (v1 - mu) * rs * gv.y + bv.y;
    o.z = (v2 - mu) * rs * gv.z + bv.z;
    o.w = (v3 - mu) * rs * gv.w + bv.w;
    *(float4*)(out + g * 256 + lane * 4) = o;
  }
}

extern "C" void kernel_launch(void* const* d_in, const int* in_sizes, int n_in,
                              void* d_out, int out_size, void* d_ws, size_t ws_size,
                              hipStream_t stream) {
  const float* x      = (const float*)d_in[0];
  const int*   adj    = (const int*)d_in[1];
  const float* W      = (const float*)d_in[2];
  const float* a_src  = (const float*)d_in[3];
  const float* a_dst  = (const float*)d_in[4];
  const float* Wo     = (const float*)d_in[5];
  const float* bo     = (const float*)d_in[6];
  const float* gamma  = (const float*)d_in[7];
  const float* beta   = (const float*)d_in[8];
  float* out = (float*)d_out;

  char* ws = (char*)d_ws;
  unsigned short* xbf       = (unsigned short*)(ws);
  unsigned short* hT        = (unsigned short*)(ws + (4u << 20));
  unsigned short* attb      = (unsigned short*)(ws + (8u << 20));
  unsigned long long* bits  = (unsigned long long*)(ws + (12u << 20));
  unsigned short* Wbf       = (unsigned short*)(ws + (12u << 20) + (512u << 10));
  unsigned short* Wobf      = (unsigned short*)(ws + (12u << 20) + (640u << 10));
  float* srcv               = (float*)(ws + (12u << 20) + (768u << 10));
  float* dstv               = (float*)(ws + (12u << 20) + (896u << 10));

  k_prep_pack<<<18560, 256, 0, stream>>>(x, W, Wo, adj, xbf, Wbf, Wobf, bits);
  k_gemm1<<<dim3(128, 4), 256, 0, stream>>>(xbf, Wbf, a_src, a_dst, hT, srcv, dstv);
  k_attn<<<512, 512, 0, stream>>>(hT, srcv, dstv, bits, attb);
  k_gemm2<<<256, 256, 0, stream>>>(attb, Wobf, bo, x, gamma, beta, out);
}